// Round 4
// baseline (8396.939 us; speedup 1.0000x reference)
//
#include <hip/hip_runtime.h>
#include <math.h>

#define B_    256
#define S_    128
#define I_    1024
#define H_    512
#define G3_   1536   // 3*H
#define SENT_ 256
#define DOC_  512
#define CH_   16     // time-chunk length for xp staging

__device__ __forceinline__ float sigmoidf_(float x) { return 1.f / (1.f + expf(-x)); }

// ---------------------------------------------------------------------------
// Chunked input projection: for chunk starting at time c0, compute
//   dir 0: xq[0*CH+tl][b][:] = x[b][c0+tl] @ Wf^T + bf        (tl in [0,16))
//   dir 1: xq[1*CH+tl][b][:] = x[b][127-(c0+tl)] @ Wb^T + bb
// 128x128 tile, BK=16, 256 threads, 8x8 micro-tile. grid = 2*32*12 = 768.
// ---------------------------------------------------------------------------
__global__ __launch_bounds__(256) void xp_gemm_kernel(
    const float* __restrict__ x,
    const float* __restrict__ Wf, const float* __restrict__ Wb,
    const float* __restrict__ bf, const float* __restrict__ bb,
    float* __restrict__ xq, int c0)
{
    const int nt   = blockIdx.x % 12;
    const int rest = blockIdx.x / 12;      // [0,64)
    const int dir  = rest >> 5;
    const int mt   = rest & 31;
    const int m0   = mt * 128;             // row within this dir's 4096-row slab
    const int n0   = nt * 128;
    const int tl   = m0 >> 8;              // 0..15 (each tl covers 256 b-rows)
    const int b0x  = m0 & 255;             // 0 or 128
    const int s    = dir ? (S_ - 1 - (c0 + tl)) : (c0 + tl);
    const float* __restrict__ W    = dir ? Wb : Wf;
    const float* __restrict__ bias = dir ? bb : bf;
    float* __restrict__ outp = xq + (size_t)(dir * CH_ + tl) * B_ * G3_;

    __shared__ float Al[16][132];   // [k][m] pad 132 -> <=2-way bank alias
    __shared__ float Bl[16][132];   // [k][n]

    const int tid = threadIdx.x;
    const int tx = tid & 15, ty = tid >> 4;
    float acc[8][8] = {};

    for (int k0 = 0; k0 < I_; k0 += 16) {
        #pragma unroll
        for (int u = 0; u < 2; ++u) {       // stage A: 128 rows x 16 k
            const int fi = u * 256 + tid;
            const int r = fi >> 2, k4 = (fi & 3) * 4;
            const float4 v = *(const float4*)
                &x[((size_t)(b0x + r) * S_ + s) * (size_t)I_ + k0 + k4];
            Al[k4+0][r] = v.x; Al[k4+1][r] = v.y; Al[k4+2][r] = v.z; Al[k4+3][r] = v.w;
        }
        #pragma unroll
        for (int u = 0; u < 2; ++u) {       // stage B: 128 cols x 16 k
            const int fi = u * 256 + tid;
            const int c = fi >> 2, k4 = (fi & 3) * 4;
            const float4 v = *(const float4*)&W[(size_t)(n0 + c) * I_ + k0 + k4];
            Bl[k4+0][c] = v.x; Bl[k4+1][c] = v.y; Bl[k4+2][c] = v.z; Bl[k4+3][c] = v.w;
        }
        __syncthreads();
        #pragma unroll
        for (int k = 0; k < 16; ++k) {
            const float4 a0 = *(const float4*)&Al[k][ty * 4];
            const float4 a1 = *(const float4*)&Al[k][64 + ty * 4];
            const float4 b0 = *(const float4*)&Bl[k][tx * 4];
            const float4 b1 = *(const float4*)&Bl[k][64 + tx * 4];
            const float av[8] = {a0.x,a0.y,a0.z,a0.w,a1.x,a1.y,a1.z,a1.w};
            const float bv[8] = {b0.x,b0.y,b0.z,b0.w,b1.x,b1.y,b1.z,b1.w};
            #pragma unroll
            for (int i = 0; i < 8; ++i)
                #pragma unroll
                for (int jj = 0; jj < 8; ++jj)
                    acc[i][jj] += av[i] * bv[jj];
        }
        __syncthreads();
    }

    #pragma unroll
    for (int i = 0; i < 8; ++i) {
        const int rloc = (i < 4) ? (ty * 4 + i) : (64 + ty * 4 + (i - 4));
        const int b = b0x + rloc;
        #pragma unroll
        for (int cgv = 0; cgv < 2; ++cgv) {
            const int n = n0 + cgv * 64 + tx * 4;
            const float4 o = { acc[i][cgv*4+0] + bias[n+0],
                               acc[i][cgv*4+1] + bias[n+1],
                               acc[i][cgv*4+2] + bias[n+2],
                               acc[i][cgv*4+3] + bias[n+3] };
            *(float4*)&outp[(size_t)b * G3_ + n] = o;
        }
    }
}

// ---------------------------------------------------------------------------
// sent = relu(rnn @ W_sent^T + b_sent).  M=32768 (rows b*128+s), N=256, K=1024.
// grid = 256 mtiles * 2 ntiles = 512.
// ---------------------------------------------------------------------------
__global__ __launch_bounds__(256) void sent_gemm_kernel(
    const float* __restrict__ A, const float* __restrict__ W,
    const float* __restrict__ bias, float* __restrict__ outp)
{
    const int nt = blockIdx.x & 1;
    const int mt = blockIdx.x >> 1;
    const int m0 = mt * 128, n0 = nt * 128;
    constexpr int K = 1024;

    __shared__ float Al[16][132];
    __shared__ float Bl[16][132];
    const int tid = threadIdx.x;
    const int tx = tid & 15, ty = tid >> 4;
    float acc[8][8] = {};

    for (int k0 = 0; k0 < K; k0 += 16) {
        #pragma unroll
        for (int u = 0; u < 2; ++u) {
            const int fi = u * 256 + tid;
            const int r = fi >> 2, k4 = (fi & 3) * 4;
            const float4 v = *(const float4*)&A[(size_t)(m0 + r) * K + k0 + k4];
            Al[k4+0][r] = v.x; Al[k4+1][r] = v.y; Al[k4+2][r] = v.z; Al[k4+3][r] = v.w;
        }
        #pragma unroll
        for (int u = 0; u < 2; ++u) {
            const int fi = u * 256 + tid;
            const int c = fi >> 2, k4 = (fi & 3) * 4;
            const float4 v = *(const float4*)&W[(size_t)(n0 + c) * K + k0 + k4];
            Bl[k4+0][c] = v.x; Bl[k4+1][c] = v.y; Bl[k4+2][c] = v.z; Bl[k4+3][c] = v.w;
        }
        __syncthreads();
        #pragma unroll
        for (int k = 0; k < 16; ++k) {
            const float4 a0 = *(const float4*)&Al[k][ty * 4];
            const float4 a1 = *(const float4*)&Al[k][64 + ty * 4];
            const float4 b0 = *(const float4*)&Bl[k][tx * 4];
            const float4 b1 = *(const float4*)&Bl[k][64 + tx * 4];
            const float av[8] = {a0.x,a0.y,a0.z,a0.w,a1.x,a1.y,a1.z,a1.w};
            const float bv[8] = {b0.x,b0.y,b0.z,b0.w,b1.x,b1.y,b1.z,b1.w};
            #pragma unroll
            for (int i = 0; i < 8; ++i)
                #pragma unroll
                for (int jj = 0; jj < 8; ++jj)
                    acc[i][jj] += av[i] * bv[jj];
        }
        __syncthreads();
    }

    #pragma unroll
    for (int i = 0; i < 8; ++i) {
        const int m = m0 + ((i < 4) ? (ty * 4 + i) : (64 + ty * 4 + (i - 4)));
        #pragma unroll
        for (int cgv = 0; cgv < 2; ++cgv) {
            const int n = n0 + cgv * 64 + tx * 4;
            const float4 o = { fmaxf(acc[i][cgv*4+0] + bias[n+0], 0.f),
                               fmaxf(acc[i][cgv*4+1] + bias[n+1], 0.f),
                               fmaxf(acc[i][cgv*4+2] + bias[n+2], 0.f),
                               fmaxf(acc[i][cgv*4+3] + bias[n+3], 0.f) };
            *(float4*)&outp[(size_t)m * SENT_ + n] = o;
        }
    }
}

// ---------------------------------------------------------------------------
// One GRU timestep, both directions. grid 256: dir x 8 b-tiles(32) x 16
// h-slices(32). Stream ordering between launches replaces grid.sync.
// rnn layout [B][S][2H]: fwd cols 0..511, bwd 512..1023.
// ---------------------------------------------------------------------------
__global__ __launch_bounds__(256) void gru_step_kernel(
    const float* __restrict__ xq,
    const float* __restrict__ Whf, const float* __restrict__ Whb,
    const float* __restrict__ bhf, const float* __restrict__ bhb,
    float* __restrict__ rnn, int t)
{
    __shared__ float hl[32][68];      // [r][k] pad 68: aligned float4 stores
    __shared__ float wl[3][32][66];   // [g][c][k] pad 66: float2 reads

    const int bid = blockIdx.x;
    const int r8 = bid & 7;
    const int dir = (r8 < 4) ? 0 : 1;                // XCD halves split by dir
    const int idx = (bid >> 3) * 4 + (r8 & 3);       // 0..127 within direction
    const int b0 = (idx >> 4) * 32;
    const int j0 = (idx & 15) * 32;
    const float* __restrict__ Wh = dir ? Whb : Whf;
    const float* __restrict__ bh = dir ? bhb : bhf;
    const int tid = threadIdx.x;
    const int tc = tid & 31, tr = tid >> 5;
    const int rr0 = tr * 4;
    const int j = j0 + tc;
    const int tl = t & (CH_ - 1);
    const int s  = dir ? (S_ - 1 - t) : t;
    const int sp = dir ? s + 1 : s - 1;
    const float bh0 = bh[j], bh1 = bh[512 + j], bh2 = bh[1024 + j];

    float acc[4][3] = {};
    if (t > 0) {
        for (int kb = 0; kb < 8; ++kb) {
            const int k0 = kb * 64;
            #pragma unroll
            for (int u = 0; u < 2; ++u) {       // stage h_prev 32x64
                const int f = u * 256 + tid;
                const int r = f >> 4, k4 = (f & 15) * 4;
                const float4 v = *(const float4*)
                    &rnn[((size_t)(b0 + r) * S_ + sp) * 1024 + dir * 512 + k0 + k4];
                *(float4*)&hl[r][k4] = v;
            }
            #pragma unroll
            for (int u = 0; u < 6; ++u) {       // stage W slice 96x64
                const int f = u * 256 + tid;
                const int row = f >> 4, k4 = (f & 15) * 4;
                const int g = row >> 5, c = row & 31;
                const float4 v = *(const float4*)
                    &Wh[((size_t)(g * 512 + j0 + c)) * 512 + k0 + k4];
                wl[g][c][k4+0] = v.x; wl[g][c][k4+1] = v.y;
                wl[g][c][k4+2] = v.z; wl[g][c][k4+3] = v.w;
            }
            __syncthreads();
            #pragma unroll
            for (int k = 0; k < 64; k += 2) {
                const float2 h0 = *(const float2*)&hl[rr0+0][k];
                const float2 h1 = *(const float2*)&hl[rr0+1][k];
                const float2 h2 = *(const float2*)&hl[rr0+2][k];
                const float2 h3 = *(const float2*)&hl[rr0+3][k];
                #pragma unroll
                for (int g = 0; g < 3; ++g) {
                    const float2 w = *(const float2*)&wl[g][tc][k];
                    acc[0][g] += h0.x * w.x + h0.y * w.y;
                    acc[1][g] += h1.x * w.x + h1.y * w.y;
                    acc[2][g] += h2.x * w.x + h2.y * w.y;
                    acc[3][g] += h3.x * w.x + h3.y * w.y;
                }
            }
            __syncthreads();
        }
    }

    const float* __restrict__ xp = xq + (size_t)(dir * CH_ + tl) * B_ * G3_;
    #pragma unroll
    for (int i = 0; i < 4; ++i) {
        const int b = b0 + rr0 + i;
        const size_t xbase = (size_t)b * G3_ + j;
        const float xr = xp[xbase];
        const float xz = xp[xbase + 512];
        const float xn = xp[xbase + 1024];
        const float r_ = sigmoidf_(xr + acc[i][0] + bh0);
        const float z_ = sigmoidf_(xz + acc[i][1] + bh1);
        const float n_ = tanhf(xn + r_ * (acc[i][2] + bh2));
        const float hp = (t == 0) ? 0.f
            : rnn[((size_t)b * S_ + sp) * 1024 + dir * 512 + j];
        rnn[((size_t)b * S_ + s) * 1024 + dir * 512 + j] = (1.f - z_) * n_ + z_ * hp;
    }
}

// ---------------------------------------------------------------------------
__global__ __launch_bounds__(256) void avg_kernel(
    const float* __restrict__ sent, const int* __restrict__ ns, float* __restrict__ avg)
{
    const int b = blockIdx.x, jj = threadIdx.x;
    float a = 0.f;
    for (int s = 0; s < S_; ++s) a += sent[((size_t)b * S_ + s) * SENT_ + jj];
    avg[b * SENT_ + jj] = a / (float)ns[b];
}

__global__ __launch_bounds__(256) void doc_kernel(
    const float* __restrict__ avg,
    const float* __restrict__ W1, const float* __restrict__ b1,
    const float* __restrict__ W2, const float* __restrict__ b2,
    float* __restrict__ doc)
{
    const int b = blockIdx.x, tid = threadIdx.x;
    __shared__ float al[SENT_];
    __shared__ float t1[DOC_];
    al[tid] = avg[b * SENT_ + tid];
    __syncthreads();
    #pragma unroll
    for (int o = 0; o < 2; ++o) {
        const int row = o * 256 + tid;
        float acc = b1[row];
        for (int i = 0; i < SENT_; i += 4) {
            const float4 wv = *(const float4*)&W1[(size_t)row * SENT_ + i];
            acc += wv.x * al[i] + wv.y * al[i+1] + wv.z * al[i+2] + wv.w * al[i+3];
        }
        t1[row] = tanhf(acc);
    }
    __syncthreads();
    float acc = b2[tid];
    for (int i = 0; i < DOC_; i += 4) {
        const float4 wv = *(const float4*)&W2[(size_t)tid * DOC_ + i];
        acc += wv.x * t1[i] + wv.y * t1[i+1] + wv.z * t1[i+2] + wv.w * t1[i+3];
    }
    doc[b * SENT_ + tid] = acc;
}

__global__ __launch_bounds__(256) void static_kernel(
    const float* __restrict__ sent, const float* __restrict__ doc,
    const float* __restrict__ Wc, const float* __restrict__ bC,
    const float* __restrict__ pose, const float* __restrict__ Wpos,
    const float* __restrict__ sege, const float* __restrict__ Wseg,
    const float* __restrict__ biasp, const int* __restrict__ ns,
    float* __restrict__ statb)
{
    const int w = threadIdx.x >> 6, lane = threadIdx.x & 63;
    const int m = blockIdx.x * 4 + w;
    const int b = m >> 7, s = m & 127;
    const float4 se = *(const float4*)&sent[(size_t)m * SENT_ + lane * 4];
    const float4 wc = *(const float4*)&Wc[lane * 4];
    const float4 dc = *(const float4*)&doc[(size_t)b * SENT_ + lane * 4];
    float p = se.x * (wc.x + dc.x) + se.y * (wc.y + dc.y)
            + se.z * (wc.z + dc.z) + se.w * (wc.w + dc.w);
    if (lane < 50) {
        const int pidx = min(s + 1, 25);
        p += pose[pidx * 50 + lane] * Wpos[lane];
        const float chunk = rintf((float)ns[b] / 4.0f);   // jnp.round = rint
        float relf = ceilf((float)(s + 1) / chunk);
        relf = fminf(fmaxf(relf, 0.f), 4.f);
        const int rel = (int)relf;
        p += sege[rel * 50 + lane] * Wseg[lane];
    }
    #pragma unroll
    for (int o = 32; o > 0; o >>= 1) p += __shfl_down(p, o, 64);
    if (lane == 0) statb[m] = p + bC[0] + biasp[0];
}

__global__ __launch_bounds__(256) void scan_kernel(
    const float* __restrict__ sent, const float* __restrict__ statb,
    const float* __restrict__ Wsim, float* __restrict__ out)
{
    const int b = blockIdx.x;
    const int jj = threadIdx.x;
    __shared__ float summ[SENT_];
    __shared__ float sv[SENT_];
    __shared__ float red[4];
    summ[jj] = 0.f;
    __syncthreads();
    for (int t = 0; t < S_; ++t) {
        const float th = tanhf(summ[jj]);
        sv[jj] = sent[((size_t)b * S_ + t) * SENT_ + jj];
        __syncthreads();
        float a0 = 0.f, a1 = 0.f, a2 = 0.f, a3 = 0.f;
        #pragma unroll 4
        for (int i = 0; i < SENT_; i += 4) {
            a0 += sv[i+0] * Wsim[(i+0) * SENT_ + jj];
            a1 += sv[i+1] * Wsim[(i+1) * SENT_ + jj];
            a2 += sv[i+2] * Wsim[(i+2) * SENT_ + jj];
            a3 += sv[i+3] * Wsim[(i+3) * SENT_ + jj];
        }
        float m = (a0 + a1 + a2 + a3) * th;
        #pragma unroll
        for (int o = 32; o > 0; o >>= 1) m += __shfl_down(m, o, 64);
        if ((jj & 63) == 0) red[jj >> 6] = m;
        __syncthreads();
        const float nov = -(red[0] + red[1] + red[2] + red[3]);
        const float logit = statb[b * S_ + t] + nov;
        const float sig = sigmoidf_(logit);
        summ[jj] += sv[jj] * sig;
        if (jj == 0) out[b * S_ + t] = logit;
        __syncthreads();
    }
}

// ---------------------------------------------------------------------------
extern "C" void kernel_launch(void* const* d_in, const int* in_sizes, int n_in,
                              void* d_out, int out_size, void* d_ws, size_t ws_size,
                              hipStream_t stream)
{
    const float* x     = (const float*)d_in[0];
    const int*   ns    = (const int*)  d_in[1];
    const float* Wihf  = (const float*)d_in[2];
    const float* Whhf  = (const float*)d_in[3];
    const float* bihf  = (const float*)d_in[4];
    const float* bhhf  = (const float*)d_in[5];
    const float* Wihb  = (const float*)d_in[6];
    const float* Whhb  = (const float*)d_in[7];
    const float* bihb  = (const float*)d_in[8];
    const float* bhhb  = (const float*)d_in[9];
    const float* Wsent = (const float*)d_in[10];
    const float* bsent = (const float*)d_in[11];
    const float* Wcont = (const float*)d_in[12];
    const float* bcont = (const float*)d_in[13];
    const float* Wdoc1 = (const float*)d_in[14];
    const float* bdoc1 = (const float*)d_in[15];
    const float* Wdoc2 = (const float*)d_in[16];
    const float* bdoc2 = (const float*)d_in[17];
    const float* Wsim  = (const float*)d_in[18];
    const float* biasp = (const float*)d_in[19];
    const float* pose  = (const float*)d_in[20];
    const float* Wpos  = (const float*)d_in[21];
    const float* sege  = (const float*)d_in[22];
    const float* Wseg  = (const float*)d_in[23];
    float* out = (float*)d_out;

    // Workspace layout (fp32): total ~185.5 MB
    //   rnn     [B,S,1024]            134.2 MB
    //   region0 max(xq, sent)          50.3 MB   (xq dead before sent written)
    //   statb/avg/doc                   0.7 MB
    float* ws      = (float*)d_ws;
    float* rnn     = ws;                                   // [B,S,1024]
    float* region0 = rnn + (size_t)B_ * S_ * (2 * H_);
    float* xq      = region0;                              // [2*CH, B, 1536]
    float* sent    = region0;                              // [B,S,256] (alias)
    float* statb   = region0 + (size_t)2 * CH_ * B_ * G3_; // [B,S]
    float* avg     = statb + (size_t)B_ * S_;              // [B,256]
    float* doc     = avg + (size_t)B_ * SENT_;             // [B,256]

    // 1+2) chunked input projection interleaved with the recurrence
    for (int c = 0; c < S_ / CH_; ++c) {
        xp_gemm_kernel<<<dim3(768), dim3(256), 0, stream>>>(
            x, Wihf, Wihb, bihf, bihb, xq, c * CH_);
        for (int tl = 0; tl < CH_; ++tl) {
            gru_step_kernel<<<dim3(256), dim3(256), 0, stream>>>(
                xq, Whhf, Whhb, bhhf, bhhb, rnn, c * CH_ + tl);
        }
    }

    // 3) sent = relu(rnn @ W_sent^T + b_sent)   (overwrites xq region)
    sent_gemm_kernel<<<dim3(512), dim3(256), 0, stream>>>(rnn, Wsent, bsent, sent);

    // 4) document representation pipeline
    avg_kernel<<<dim3(256), dim3(256), 0, stream>>>(sent, ns, avg);
    doc_kernel<<<dim3(256), dim3(256), 0, stream>>>(avg, Wdoc1, bdoc1, Wdoc2, bdoc2, doc);
    static_kernel<<<dim3(8192), dim3(256), 0, stream>>>(
        sent, doc, Wcont, bcont, pose, Wpos, sege, Wseg, biasp, ns, statb);

    // 5) sequential novelty scan -> logits
    scan_kernel<<<dim3(256), dim3(256), 0, stream>>>(sent, statb, Wsim, out);
}

// Round 7
// 7604.715 us; speedup vs baseline: 1.1042x; 1.1042x over previous
//
#include <hip/hip_runtime.h>
#include <math.h>

#define B_    256
#define S_    128
#define I_    1024
#define H_    512
#define G3_   1536   // 3*H
#define SENT_ 256
#define DOC_  512
#define CH_   16     // time-chunk length for xp staging

__device__ __forceinline__ float sigmoidf_(float x) { return 1.f / (1.f + expf(-x)); }

// ---------------------------------------------------------------------------
// Chunked input projection (unchanged from R4 baseline).
// ---------------------------------------------------------------------------
__global__ __launch_bounds__(256) void xp_gemm_kernel(
    const float* __restrict__ x,
    const float* __restrict__ Wf, const float* __restrict__ Wb,
    const float* __restrict__ bf, const float* __restrict__ bb,
    float* __restrict__ xq, int c0)
{
    const int nt   = blockIdx.x % 12;
    const int rest = blockIdx.x / 12;      // [0,64)
    const int dir  = rest >> 5;
    const int mt   = rest & 31;
    const int m0   = mt * 128;
    const int n0   = nt * 128;
    const int tl   = m0 >> 8;
    const int b0x  = m0 & 255;
    const int s    = dir ? (S_ - 1 - (c0 + tl)) : (c0 + tl);
    const float* __restrict__ W    = dir ? Wb : Wf;
    const float* __restrict__ bias = dir ? bb : bf;
    float* __restrict__ outp = xq + (size_t)(dir * CH_ + tl) * B_ * G3_;

    __shared__ float Al[16][132];
    __shared__ float Bl[16][132];

    const int tid = threadIdx.x;
    const int tx = tid & 15, ty = tid >> 4;
    float acc[8][8] = {};

    for (int k0 = 0; k0 < I_; k0 += 16) {
        #pragma unroll
        for (int u = 0; u < 2; ++u) {
            const int fi = u * 256 + tid;
            const int r = fi >> 2, k4 = (fi & 3) * 4;
            const float4 v = *(const float4*)
                &x[((size_t)(b0x + r) * S_ + s) * (size_t)I_ + k0 + k4];
            Al[k4+0][r] = v.x; Al[k4+1][r] = v.y; Al[k4+2][r] = v.z; Al[k4+3][r] = v.w;
        }
        #pragma unroll
        for (int u = 0; u < 2; ++u) {
            const int fi = u * 256 + tid;
            const int c = fi >> 2, k4 = (fi & 3) * 4;
            const float4 v = *(const float4*)&W[(size_t)(n0 + c) * I_ + k0 + k4];
            Bl[k4+0][c] = v.x; Bl[k4+1][c] = v.y; Bl[k4+2][c] = v.z; Bl[k4+3][c] = v.w;
        }
        __syncthreads();
        #pragma unroll
        for (int k = 0; k < 16; ++k) {
            const float4 a0 = *(const float4*)&Al[k][ty * 4];
            const float4 a1 = *(const float4*)&Al[k][64 + ty * 4];
            const float4 b0 = *(const float4*)&Bl[k][tx * 4];
            const float4 b1 = *(const float4*)&Bl[k][64 + tx * 4];
            const float av[8] = {a0.x,a0.y,a0.z,a0.w,a1.x,a1.y,a1.z,a1.w};
            const float bv[8] = {b0.x,b0.y,b0.z,b0.w,b1.x,b1.y,b1.z,b1.w};
            #pragma unroll
            for (int i = 0; i < 8; ++i)
                #pragma unroll
                for (int jj = 0; jj < 8; ++jj)
                    acc[i][jj] += av[i] * bv[jj];
        }
        __syncthreads();
    }

    #pragma unroll
    for (int i = 0; i < 8; ++i) {
        const int rloc = (i < 4) ? (ty * 4 + i) : (64 + ty * 4 + (i - 4));
        const int b = b0x + rloc;
        #pragma unroll
        for (int cgv = 0; cgv < 2; ++cgv) {
            const int n = n0 + cgv * 64 + tx * 4;
            const float4 o = { acc[i][cgv*4+0] + bias[n+0],
                               acc[i][cgv*4+1] + bias[n+1],
                               acc[i][cgv*4+2] + bias[n+2],
                               acc[i][cgv*4+3] + bias[n+3] };
            *(float4*)&outp[(size_t)b * G3_ + n] = o;
        }
    }
}

// ---------------------------------------------------------------------------
// sent = relu(rnn @ W_sent^T + b_sent) (unchanged). M=32768, N=256, K=1024.
// ---------------------------------------------------------------------------
__global__ __launch_bounds__(256) void sent_gemm_kernel(
    const float* __restrict__ A, const float* __restrict__ W,
    const float* __restrict__ bias, float* __restrict__ outp)
{
    const int nt = blockIdx.x & 1;
    const int mt = blockIdx.x >> 1;
    const int m0 = mt * 128, n0 = nt * 128;
    constexpr int K = 1024;

    __shared__ float Al[16][132];
    __shared__ float Bl[16][132];
    const int tid = threadIdx.x;
    const int tx = tid & 15, ty = tid >> 4;
    float acc[8][8] = {};

    for (int k0 = 0; k0 < K; k0 += 16) {
        #pragma unroll
        for (int u = 0; u < 2; ++u) {
            const int fi = u * 256 + tid;
            const int r = fi >> 2, k4 = (fi & 3) * 4;
            const float4 v = *(const float4*)&A[(size_t)(m0 + r) * K + k0 + k4];
            Al[k4+0][r] = v.x; Al[k4+1][r] = v.y; Al[k4+2][r] = v.z; Al[k4+3][r] = v.w;
        }
        #pragma unroll
        for (int u = 0; u < 2; ++u) {
            const int fi = u * 256 + tid;
            const int c = fi >> 2, k4 = (fi & 3) * 4;
            const float4 v = *(const float4*)&W[(size_t)(n0 + c) * K + k0 + k4];
            Bl[k4+0][c] = v.x; Bl[k4+1][c] = v.y; Bl[k4+2][c] = v.z; Bl[k4+3][c] = v.w;
        }
        __syncthreads();
        #pragma unroll
        for (int k = 0; k < 16; ++k) {
            const float4 a0 = *(const float4*)&Al[k][ty * 4];
            const float4 a1 = *(const float4*)&Al[k][64 + ty * 4];
            const float4 b0 = *(const float4*)&Bl[k][tx * 4];
            const float4 b1 = *(const float4*)&Bl[k][64 + tx * 4];
            const float av[8] = {a0.x,a0.y,a0.z,a0.w,a1.x,a1.y,a1.z,a1.w};
            const float bv[8] = {b0.x,b0.y,b0.z,b0.w,b1.x,b1.y,b1.z,b1.w};
            #pragma unroll
            for (int i = 0; i < 8; ++i)
                #pragma unroll
                for (int jj = 0; jj < 8; ++jj)
                    acc[i][jj] += av[i] * bv[jj];
        }
        __syncthreads();
    }

    #pragma unroll
    for (int i = 0; i < 8; ++i) {
        const int m = m0 + ((i < 4) ? (ty * 4 + i) : (64 + ty * 4 + (i - 4)));
        #pragma unroll
        for (int cgv = 0; cgv < 2; ++cgv) {
            const int n = n0 + cgv * 64 + tx * 4;
            const float4 o = { fmaxf(acc[i][cgv*4+0] + bias[n+0], 0.f),
                               fmaxf(acc[i][cgv*4+1] + bias[n+1], 0.f),
                               fmaxf(acc[i][cgv*4+2] + bias[n+2], 0.f),
                               fmaxf(acc[i][cgv*4+3] + bias[n+3], 0.f) };
            *(float4*)&outp[(size_t)m * SENT_ + n] = o;
        }
    }
}

// ---------------------------------------------------------------------------
// P = sent @ W_sim   (W accessed [k][n], i.e. NOT transposed).
// M=32768, N=256, K=256. grid = 256 mtiles * 2 ntiles = 512.
// ---------------------------------------------------------------------------
__global__ __launch_bounds__(256) void p_gemm_kernel(
    const float* __restrict__ A, const float* __restrict__ W,
    float* __restrict__ outp)
{
    const int nt = blockIdx.x & 1;
    const int mt = blockIdx.x >> 1;
    const int m0 = mt * 128, n0 = nt * 128;
    constexpr int K = 256;

    __shared__ float Al[16][132];
    __shared__ float Bl[16][132];
    const int tid = threadIdx.x;
    const int tx = tid & 15, ty = tid >> 4;
    float acc[8][8] = {};

    for (int k0 = 0; k0 < K; k0 += 16) {
        #pragma unroll
        for (int u = 0; u < 2; ++u) {           // A: 128 rows x 16 k
            const int fi = u * 256 + tid;
            const int r = fi >> 2, k4 = (fi & 3) * 4;
            const float4 v = *(const float4*)&A[(size_t)(m0 + r) * K + k0 + k4];
            Al[k4+0][r] = v.x; Al[k4+1][r] = v.y; Al[k4+2][r] = v.z; Al[k4+3][r] = v.w;
        }
        #pragma unroll
        for (int u = 0; u < 2; ++u) {           // B: 16 k x 128 n (row-major W)
            const int fi = u * 256 + tid;
            const int kr = fi >> 5, c4 = (fi & 31) * 4;
            const float4 v = *(const float4*)&W[(size_t)(k0 + kr) * SENT_ + n0 + c4];
            *(float4*)&Bl[kr][c4] = v;
        }
        __syncthreads();
        #pragma unroll
        for (int k = 0; k < 16; ++k) {
            const float4 a0 = *(const float4*)&Al[k][ty * 4];
            const float4 a1 = *(const float4*)&Al[k][64 + ty * 4];
            const float4 b0 = *(const float4*)&Bl[k][tx * 4];
            const float4 b1 = *(const float4*)&Bl[k][64 + tx * 4];
            const float av[8] = {a0.x,a0.y,a0.z,a0.w,a1.x,a1.y,a1.z,a1.w};
            const float bv[8] = {b0.x,b0.y,b0.z,b0.w,b1.x,b1.y,b1.z,b1.w};
            #pragma unroll
            for (int i = 0; i < 8; ++i)
                #pragma unroll
                for (int jj = 0; jj < 8; ++jj)
                    acc[i][jj] += av[i] * bv[jj];
        }
        __syncthreads();
    }

    #pragma unroll
    for (int i = 0; i < 8; ++i) {
        const int m = m0 + ((i < 4) ? (ty * 4 + i) : (64 + ty * 4 + (i - 4)));
        #pragma unroll
        for (int cgv = 0; cgv < 2; ++cgv) {
            const int n = n0 + cgv * 64 + tx * 4;
            const float4 o = { acc[i][cgv*4+0], acc[i][cgv*4+1],
                               acc[i][cgv*4+2], acc[i][cgv*4+3] };
            *(float4*)&outp[(size_t)m * SENT_ + n] = o;
        }
    }
}

// ---------------------------------------------------------------------------
// One GRU timestep, both directions. 512 blocks (2 blocks/CU) each
// 32 batches x 16 j-cols: dir x 8 b-tiles(32) x 32 j-slices(16).
// rnn layout [B][S][2H]: fwd cols 0..511, bwd 512..1023.
// ---------------------------------------------------------------------------
__global__ __launch_bounds__(256) void gru_step_kernel(
    const float* __restrict__ xq,
    const float* __restrict__ Whf, const float* __restrict__ Whb,
    const float* __restrict__ bhf, const float* __restrict__ bhb,
    float* __restrict__ rnn, int t)
{
    __shared__ float hl[32][68];      // [b-row][k]  pad 68
    __shared__ float wl[3][16][66];   // [g][c][k]   pad 66

    const int bid = blockIdx.x;
    const int r8 = bid & 7;
    const int dir = (r8 < 4) ? 0 : 1;                // XCD halves split by dir
    const int idx = (bid >> 3) * 4 + (r8 & 3);       // 0..255 within direction
    const int b0 = (idx >> 5) * 32;                  // 8 b-tiles of 32
    const int j0 = (idx & 31) * 16;                  // 32 j-slices of 16
    const float* __restrict__ Wh = dir ? Whb : Whf;
    const float* __restrict__ bh = dir ? bhb : bhf;
    const int tid = threadIdx.x;
    const int tc = tid & 15, tr = tid >> 4;          // j-off, b-group
    const int rr0 = tr * 2;                          // 2 b-rows per thread
    const int j = j0 + tc;
    const int tl = t & (CH_ - 1);
    const int s  = dir ? (S_ - 1 - t) : t;
    const int sp = dir ? s + 1 : s - 1;
    const float bh0 = bh[j], bh1 = bh[512 + j], bh2 = bh[1024 + j];

    float acc[2][3] = {};
    if (t > 0) {
        for (int kb = 0; kb < 8; ++kb) {
            const int k0 = kb * 64;
            #pragma unroll
            for (int u = 0; u < 2; ++u) {       // stage h_prev 32x64
                const int f = u * 256 + tid;
                const int r = f >> 4, k4 = (f & 15) * 4;
                const float4 v = *(const float4*)
                    &rnn[((size_t)(b0 + r) * S_ + sp) * 1024 + dir * 512 + k0 + k4];
                *(float4*)&hl[r][k4] = v;
            }
            #pragma unroll
            for (int u = 0; u < 3; ++u) {       // stage W slice 48x64
                const int f = u * 256 + tid;
                const int row = f >> 4, k4 = (f & 15) * 4;
                const int g = row >> 4, c = row & 15;
                const float4 v = *(const float4*)
                    &Wh[((size_t)(g * 512 + j0 + c)) * 512 + k0 + k4];
                wl[g][c][k4+0] = v.x; wl[g][c][k4+1] = v.y;
                wl[g][c][k4+2] = v.z; wl[g][c][k4+3] = v.w;
            }
            __syncthreads();
            #pragma unroll
            for (int k = 0; k < 64; k += 2) {
                const float2 h0 = *(const float2*)&hl[rr0+0][k];
                const float2 h1 = *(const float2*)&hl[rr0+1][k];
                #pragma unroll
                for (int g = 0; g < 3; ++g) {
                    const float2 w = *(const float2*)&wl[g][tc][k];
                    acc[0][g] += h0.x * w.x + h0.y * w.y;
                    acc[1][g] += h1.x * w.x + h1.y * w.y;
                }
            }
            __syncthreads();
        }
    }

    const float* __restrict__ xp = xq + (size_t)(dir * CH_ + tl) * B_ * G3_;
    #pragma unroll
    for (int i = 0; i < 2; ++i) {
        const int b = b0 + rr0 + i;
        const size_t xbase = (size_t)b * G3_ + j;
        const float xr = xp[xbase];
        const float xz = xp[xbase + 512];
        const float xn = xp[xbase + 1024];
        const float r_ = sigmoidf_(xr + acc[i][0] + bh0);
        const float z_ = sigmoidf_(xz + acc[i][1] + bh1);
        const float n_ = tanhf(xn + r_ * (acc[i][2] + bh2));
        const float hp = (t == 0) ? 0.f
            : rnn[((size_t)b * S_ + sp) * 1024 + dir * 512 + j];
        rnn[((size_t)b * S_ + s) * 1024 + dir * 512 + j] = (1.f - z_) * n_ + z_ * hp;
    }
}

// ---------------------------------------------------------------------------
__global__ __launch_bounds__(256) void avg_kernel(
    const float* __restrict__ sent, const int* __restrict__ ns, float* __restrict__ avg)
{
    const int b = blockIdx.x, jj = threadIdx.x;
    float a = 0.f;
    for (int s = 0; s < S_; ++s) a += sent[((size_t)b * S_ + s) * SENT_ + jj];
    avg[b * SENT_ + jj] = a / (float)ns[b];
}

__global__ __launch_bounds__(256) void doc_kernel(
    const float* __restrict__ avg,
    const float* __restrict__ W1, const float* __restrict__ b1,
    const float* __restrict__ W2, const float* __restrict__ b2,
    float* __restrict__ doc)
{
    const int b = blockIdx.x, tid = threadIdx.x;
    __shared__ float al[SENT_];
    __shared__ float t1[DOC_];
    al[tid] = avg[b * SENT_ + tid];
    __syncthreads();
    #pragma unroll
    for (int o = 0; o < 2; ++o) {
        const int row = o * 256 + tid;
        float acc = b1[row];
        for (int i = 0; i < SENT_; i += 4) {
            const float4 wv = *(const float4*)&W1[(size_t)row * SENT_ + i];
            acc += wv.x * al[i] + wv.y * al[i+1] + wv.z * al[i+2] + wv.w * al[i+3];
        }
        t1[row] = tanhf(acc);
    }
    __syncthreads();
    float acc = b2[tid];
    for (int i = 0; i < DOC_; i += 4) {
        const float4 wv = *(const float4*)&W2[(size_t)tid * DOC_ + i];
        acc += wv.x * t1[i] + wv.y * t1[i+1] + wv.z * t1[i+2] + wv.w * t1[i+3];
    }
    doc[b * SENT_ + tid] = acc;
}

__global__ __launch_bounds__(256) void static_kernel(
    const float* __restrict__ sent, const float* __restrict__ doc,
    const float* __restrict__ Wc, const float* __restrict__ bC,
    const float* __restrict__ pose, const float* __restrict__ Wpos,
    const float* __restrict__ sege, const float* __restrict__ Wseg,
    const float* __restrict__ biasp, const int* __restrict__ ns,
    float* __restrict__ statb)
{
    const int w = threadIdx.x >> 6, lane = threadIdx.x & 63;
    const int m = blockIdx.x * 4 + w;
    const int b = m >> 7, s = m & 127;
    const float4 se = *(const float4*)&sent[(size_t)m * SENT_ + lane * 4];
    const float4 wc = *(const float4*)&Wc[lane * 4];
    const float4 dc = *(const float4*)&doc[(size_t)b * SENT_ + lane * 4];
    float p = se.x * (wc.x + dc.x) + se.y * (wc.y + dc.y)
            + se.z * (wc.z + dc.z) + se.w * (wc.w + dc.w);
    if (lane < 50) {
        const int pidx = min(s + 1, 25);
        p += pose[pidx * 50 + lane] * Wpos[lane];
        const float chunk = rintf((float)ns[b] / 4.0f);   // jnp.round = rint
        float relf = ceilf((float)(s + 1) / chunk);
        relf = fminf(fmaxf(relf, 0.f), 4.f);
        const int rel = (int)relf;
        p += sege[rel * 50 + lane] * Wseg[lane];
    }
    #pragma unroll
    for (int o = 32; o > 0; o >>= 1) p += __shfl_down(p, o, 64);
    if (lane == 0) statb[m] = p + bC[0] + biasp[0];
}

// ---------------------------------------------------------------------------
// Light scan: nov_t = -sum_j P[b,t,j] * tanh(summ_j).
// One wave per batch; summ entirely in registers (float4/lane). No LDS/syncs.
// ---------------------------------------------------------------------------
__global__ __launch_bounds__(64) void scan2_kernel(
    const float* __restrict__ sent, const float* __restrict__ P,
    const float* __restrict__ statb, float* __restrict__ out)
{
    const int b = blockIdx.x;
    const int lane = threadIdx.x;
    float4 summ = {0.f, 0.f, 0.f, 0.f};
    for (int t = 0; t < S_; ++t) {
        const size_t row = ((size_t)b * S_ + t) * SENT_ + lane * 4;
        const float4 pv = *(const float4*)&P[row];
        const float4 sv = *(const float4*)&sent[row];
        float m = pv.x * tanhf(summ.x) + pv.y * tanhf(summ.y)
                + pv.z * tanhf(summ.z) + pv.w * tanhf(summ.w);
        #pragma unroll
        for (int o = 1; o < 64; o <<= 1) m += __shfl_xor(m, o, 64);
        const float logit = statb[b * S_ + t] - m;
        const float sig = sigmoidf_(logit);
        summ.x += sv.x * sig; summ.y += sv.y * sig;
        summ.z += sv.z * sig; summ.w += sv.w * sig;
        if (lane == 0) out[b * S_ + t] = logit;
    }
}

// ---------------------------------------------------------------------------
extern "C" void kernel_launch(void* const* d_in, const int* in_sizes, int n_in,
                              void* d_out, int out_size, void* d_ws, size_t ws_size,
                              hipStream_t stream)
{
    const float* x     = (const float*)d_in[0];
    const int*   ns    = (const int*)  d_in[1];
    const float* Wihf  = (const float*)d_in[2];
    const float* Whhf  = (const float*)d_in[3];
    const float* bihf  = (const float*)d_in[4];
    const float* bhhf  = (const float*)d_in[5];
    const float* Wihb  = (const float*)d_in[6];
    const float* Whhb  = (const float*)d_in[7];
    const float* bihb  = (const float*)d_in[8];
    const float* bhhb  = (const float*)d_in[9];
    const float* Wsent = (const float*)d_in[10];
    const float* bsent = (const float*)d_in[11];
    const float* Wcont = (const float*)d_in[12];
    const float* bcont = (const float*)d_in[13];
    const float* Wdoc1 = (const float*)d_in[14];
    const float* bdoc1 = (const float*)d_in[15];
    const float* Wdoc2 = (const float*)d_in[16];
    const float* bdoc2 = (const float*)d_in[17];
    const float* Wsim  = (const float*)d_in[18];
    const float* biasp = (const float*)d_in[19];
    const float* pose  = (const float*)d_in[20];
    const float* Wpos  = (const float*)d_in[21];
    const float* sege  = (const float*)d_in[22];
    const float* Wseg  = (const float*)d_in[23];
    float* out = (float*)d_out;

    // Workspace layout (fp32): high-water ~185.5 MB (same as R4 known-good)
    //   rnn     [B,S,1024]   134.2 MB   -> dead after sent_gemm; reused for P
    //   region0 max(xq,sent)  50.3 MB   (xq dead before sent written)
    //   statb/avg/doc          0.7 MB
    float* ws      = (float*)d_ws;
    float* rnn     = ws;                                   // [B,S,1024]
    float* P       = ws;                                   // [B,S,256] alias (rnn dead)
    float* region0 = rnn + (size_t)B_ * S_ * (2 * H_);
    float* xq      = region0;                              // [2*CH, B, 1536]
    float* sent    = region0;                              // [B,S,256] (alias)
    float* statb   = region0 + (size_t)2 * CH_ * B_ * G3_; // [B,S]
    float* avg     = statb + (size_t)B_ * S_;              // [B,256]
    float* doc     = avg + (size_t)B_ * SENT_;             // [B,256]

    // 1+2) chunked input projection interleaved with the recurrence
    for (int c = 0; c < S_ / CH_; ++c) {
        xp_gemm_kernel<<<dim3(768), dim3(256), 0, stream>>>(
            x, Wihf, Wihb, bihf, bihb, xq, c * CH_);
        for (int tl = 0; tl < CH_; ++tl) {
            gru_step_kernel<<<dim3(512), dim3(256), 0, stream>>>(
                xq, Whhf, Whhb, bhhf, bhhb, rnn, c * CH_ + tl);
        }
    }

    // 3) sent = relu(rnn @ W_sent^T + b_sent)   (overwrites xq region)
    sent_gemm_kernel<<<dim3(512), dim3(256), 0, stream>>>(rnn, Wsent, bsent, sent);

    // 4) document representation pipeline
    avg_kernel<<<dim3(256), dim3(256), 0, stream>>>(sent, ns, avg);
    doc_kernel<<<dim3(256), dim3(256), 0, stream>>>(avg, Wdoc1, bdoc1, Wdoc2, bdoc2, doc);
    static_kernel<<<dim3(8192), dim3(256), 0, stream>>>(
        sent, doc, Wcont, bcont, pose, Wpos, sege, Wseg, biasp, ns, statb);

    // 5) P = sent @ W_sim  (into dead rnn buffer), then light register scan
    p_gemm_kernel<<<dim3(512), dim3(256), 0, stream>>>(sent, Wsim, P);
    scan2_kernel<<<dim3(256), dim3(64), 0, stream>>>(sent, P, statb, out);
}